// Round 15
// baseline (198.631 us; speedup 1.0000x reference)
//
#include <hip/hip_runtime.h>
#include <cstdint>

constexpr int Bb = 8, Hh = 512, Ww = 512;
constexpr int HWn = Hh * Ww;          // 262144 = 2^18
constexpr int CHF = 16;               // rows per block in fused k123
constexpr int CHK4 = 16;              // rows per block in k4 (groups of 4)
constexpr int NBIN = 1024;            // percentile histogram bins over [0,1]
constexpr int NSUB = 32;              // sub-blocks per (b,c) in k5_hist

__device__ __forceinline__ int reflect_idx(int p, int n) {
    p = (p < 0) ? -p : p;
    return (p < n) ? p : (2 * n - 2 - p);
}
__device__ __forceinline__ int clamp_r(const int* rad) {
    int r = rad[0];
    return (r < 1) ? 1 : ((r > 50) ? 50 : r);
}
__device__ __forceinline__ void add4(float4& a, const float4& b) {
    a.x += b.x; a.y += b.y; a.z += b.z; a.w += b.w;
}
__device__ __forceinline__ void sub4(float4& a, const float4& b) {
    a.x -= b.x; a.y -= b.y; a.z -= b.z; a.w -= b.w;
}

// ---- K123: img -> stats (on the fly) -> vertical box (slide, registers)
//      -> per-row horizontal box (scan) -> a,b -> second scan -> hab.
//      hq field and k1 kernel eliminated entirely.
__global__ __launch_bounds__(512) void k123_fused(
    const float* __restrict__ img, const float* __restrict__ omega,
    const float* __restrict__ atm, const int* __restrict__ rad,
    float2* __restrict__ hab, unsigned int* __restrict__ histzero)
{
    const int b  = blockIdx.y;
    const int y0 = blockIdx.x * CHF;
    const int j  = threadIdx.x;
    const int fbid = b * gridDim.x + blockIdx.x;   // 0..255
    if (fbid < 48) histzero[fbid * 512 + j] = 0u;  // zero 24*1024 hist bins
    const int r = clamp_r(rad);
    const float ikk = 1.0f / (float)((2*r+1) * (2*r+1));
    const int lane = j & 63, wv = j >> 6;
    const int jm1 = (j > 0) ? j - 1 : 0;

    __shared__ float4 P4[512];          // 8 KB
    __shared__ float2 P2[512];          // 4 KB
    __shared__ float4 w4s[8];
    __shared__ float2 w2s[8];

    const float om  = omega[b];
    const float iA0 = 1.0f / (atm[b*3+0] + 1e-8f);
    const float iA1 = 1.0f / (atm[b*3+1] + 1e-8f);
    const float iA2 = 1.0f / (atm[b*3+2] + 1e-8f);
    const float* imb = img + (size_t)b * 3 * HWn;

    // stats of a (reflected, real) row rr: {gray, tg, gray*tg, gray^2}
    auto stats_row = [&](int rr) -> float4 {
        const int ip = (rr > 0) ? rr - 1 : 0;
        float r0 = imb[0*HWn + rr*Ww + j];
        float g0 = imb[1*HWn + rr*Ww + j];
        float b0 = imb[2*HWn + rr*Ww + j];
        float r1 = imb[0*HWn + ip*Ww + j];
        float g1 = imb[1*HWn + ip*Ww + j];
        float b1 = imb[2*HWn + ip*Ww + j];
        float r2 = imb[0*HWn + ip*Ww + jm1];
        float g2 = imb[1*HWn + ip*Ww + jm1];
        float b2 = imb[2*HWn + ip*Ww + jm1];
        float t0c  = 1.0f - om * fminf(fminf(r0*iA0, g0*iA1), b0*iA2);
        float t0p  = 1.0f - om * fminf(fminf(r1*iA0, g1*iA1), b1*iA2);
        float t0pm = 1.0f - om * fminf(fminf(r2*iA0, g2*iA1), b2*iA2);
        // j==0: jm1==j -> exp(0)=1 -> tx=t0p (matches reference)
        float tx  = t0pm * __expf(-fabsf(t0p - t0pm));
        // rr==0: ip==rr -> t0p==t0c -> exp(0)=1 -> tgv=tx (matches reference)
        float tgv = tx * __expf(-fabsf(t0c - t0p));
        float gr  = 0.299f*r0 + 0.587f*g0 + 0.114f*b0;
        float4 s; s.x = gr; s.y = tgv; s.z = gr * tgv; s.w = gr * gr;
        return s;
    };

    // phase A: vertical sliding window over on-the-fly stats (barrier-free)
    float4 V; V.x = 0.f; V.y = 0.f; V.z = 0.f; V.w = 0.f;
    for (int d = -r; d <= r; ++d) {
        float4 s = stats_row(reflect_idx(y0 + d, Hh));
        add4(V, s);
    }
    float4 v4r[CHF];
    #pragma unroll
    for (int k = 0; k < CHF; ++k) {
        v4r[k] = V;
        float4 si = stats_row(reflect_idx(y0 + k + 1 + r, Hh));
        float4 so = stats_row(reflect_idx(y0 + k - r, Hh));
        add4(V, si); sub4(V, so);
    }

    // lookup positions (lane-constant across rows)
    const int lo = j - r, hi = j + r;
    const int him = (hi > 511) ? 511 : hi;
    const int pB = (lo > 0) ? (lo - 1) : 0;
    const int pC = (lo < 0) ? (r - j) : 0;
    const int pD = (hi > 511) ? (1021 - j - r) : 0;
    const int iA_ = him >> 6, iB_ = pB >> 6, iC_ = pC >> 6, iD_ = pD >> 6;

    // phase B: per row, scan4 -> box -> a,b -> scan2 -> box -> hab
    #pragma unroll
    for (int k = 0; k < CHF; ++k) {
        // ---- scan 1 (float4 window sums) ----
        float4 sc = v4r[k];
        #pragma unroll
        for (int off = 1; off < 64; off <<= 1) {
            float ux = __shfl_up(sc.x, off);
            float uy = __shfl_up(sc.y, off);
            float uz = __shfl_up(sc.z, off);
            float uw = __shfl_up(sc.w, off);
            if (lane >= off) { sc.x += ux; sc.y += uy; sc.z += uz; sc.w += uw; }
        }
        P4[j] = sc;
        if (lane == 63) w4s[wv] = sc;
        __syncthreads();

        float4 q0 = w4s[0], q1 = w4s[1], q2 = w4s[2], q3 = w4s[3];
        float4 q4 = w4s[4], q5 = w4s[5], q6 = w4s[6];
        #define WOFF4(idx, o)                                   \
            { o.x=0.f;o.y=0.f;o.z=0.f;o.w=0.f;                  \
              if ((idx) > 0) add4(o, q0);                       \
              if ((idx) > 1) add4(o, q1);                       \
              if ((idx) > 2) add4(o, q2);                       \
              if ((idx) > 3) add4(o, q3);                       \
              if ((idx) > 4) add4(o, q4);                       \
              if ((idx) > 5) add4(o, q5);                       \
              if ((idx) > 6) add4(o, q6); }
        float4 oA; WOFF4(iA_, oA);
        float4 s4 = P4[him]; add4(s4, oA);
        if (lo > 0) {
            float4 oB; WOFF4(iB_, oB);
            float4 t = P4[pB]; add4(t, oB);
            sub4(s4, t);
        }
        if (lo < 0) {
            float4 oC; WOFF4(iC_, oC);
            float4 t = P4[pC]; add4(t, oC);
            float4 u = P4[0];
            add4(s4, t); sub4(s4, u);
        }
        if (hi > 511) {
            float4 t = P4[510];
            float4 full; full.x=q0.x+q1.x+q2.x+q3.x+q4.x+q5.x+q6.x;
            full.y=q0.y+q1.y+q2.y+q3.y+q4.y+q5.y+q6.y;
            full.z=q0.z+q1.z+q2.z+q3.z+q4.z+q5.z+q6.z;
            full.w=q0.w+q1.w+q2.w+q3.w+q4.w+q5.w+q6.w;
            add4(t, full);
            float4 oD; WOFF4(iD_, oD);
            float4 u = P4[pD]; add4(u, oD);
            add4(s4, t); sub4(s4, u);
        }
        #undef WOFF4

        float mI = s4.x * ikk, mp = s4.y * ikk, mIp = s4.z * ikk, mII = s4.w * ikk;
        float av = (mIp - mI * mp) / (mII - mI * mI + 0.5f);
        float bv = mp - av * mI;

        // ---- scan 2 (a,b) ----
        float sx = av, sy = bv;
        #pragma unroll
        for (int off = 1; off < 64; off <<= 1) {
            float ux = __shfl_up(sx, off);
            float uy = __shfl_up(sy, off);
            if (lane >= off) { sx += ux; sy += uy; }
        }
        P2[j].x = sx; P2[j].y = sy;
        if (lane == 63) { w2s[wv].x = sx; w2s[wv].y = sy; }
        __syncthreads();

        float2 p0 = w2s[0], p1 = w2s[1], p2 = w2s[2], p3 = w2s[3];
        float2 p4 = w2s[4], p5 = w2s[5], p6 = w2s[6];
        #define WOFF2(idx, ox, oy)                              \
            { ox = 0.f; oy = 0.f;                               \
              if ((idx) > 0) { ox += p0.x; oy += p0.y; }        \
              if ((idx) > 1) { ox += p1.x; oy += p1.y; }        \
              if ((idx) > 2) { ox += p2.x; oy += p2.y; }        \
              if ((idx) > 3) { ox += p3.x; oy += p3.y; }        \
              if ((idx) > 4) { ox += p4.x; oy += p4.y; }        \
              if ((idx) > 5) { ox += p5.x; oy += p5.y; }        \
              if ((idx) > 6) { ox += p6.x; oy += p6.y; } }
        float oxA, oyA; WOFF2(iA_, oxA, oyA);
        float2 PA = P2[him];
        float hsx = PA.x + oxA, hsy = PA.y + oyA;
        if (lo > 0) {
            float oxB, oyB; WOFF2(iB_, oxB, oyB);
            float2 t = P2[pB];
            hsx -= t.x + oxB; hsy -= t.y + oyB;
        }
        if (lo < 0) {
            float oxC, oyC; WOFF2(iC_, oxC, oyC);
            float2 t = P2[pC], u = P2[0];
            hsx += (t.x + oxC) - u.x; hsy += (t.y + oyC) - u.y;
        }
        if (hi > 511) {
            float fx = p0.x+p1.x+p2.x+p3.x+p4.x+p5.x+p6.x;
            float fy = p0.y+p1.y+p2.y+p3.y+p4.y+p5.y+p6.y;
            float oxD, oyD; WOFF2(iD_, oxD, oyD);
            float2 t = P2[510], u = P2[pD];
            hsx += (t.x + fx) - (u.x + oxD);
            hsy += (t.y + fy) - (u.y + oyD);
        }
        #undef WOFF2
        hab[((size_t)b * Hh + (y0 + k)) * Ww + j] = make_float2(hsx, hsy);
    }
}

// ---- K4: vertical sliding box on hab -> t -> J, 4-row load batching ------
__global__ __launch_bounds__(256) void k4_final_v(
    const float2* __restrict__ hab, const float* __restrict__ img,
    const float* __restrict__ atm, const int* __restrict__ rad,
    float* __restrict__ J)
{
    const int b  = blockIdx.y;
    const int y0 = blockIdx.x * CHK4;
    const int j  = blockIdx.z * 256 + threadIdx.x;
    const int r  = clamp_r(rad);
    const float ikk = 1.0f / (float)((2*r+1) * (2*r+1));

    float Aa[3];
    Aa[0] = atm[b*3+0]; Aa[1] = atm[b*3+1]; Aa[2] = atm[b*3+2];
    const float* imb = img + (size_t)b * 3 * HWn;
    float* Jb = J + (size_t)b * 3 * HWn;
    const float2* habb = hab + (size_t)b * Hh * Ww + j;

    float2 V; V.x = 0.f; V.y = 0.f;
    for (int d = -r; d <= r; ++d) {
        int m = reflect_idx(y0 + d, Hh);
        float2 v = habb[(size_t)m * Ww];
        V.x += v.x; V.y += v.y;
    }

    #pragma unroll
    for (int g = 0; g < CHK4; g += 4) {
        const int yb = y0 + g;
        float2 vi[4], vo[4];
        float cr[4], cg[4], cb[4];
        #pragma unroll
        for (int q = 0; q < 4; ++q) {
            const int y = yb + q;
            vi[q] = habb[(size_t)reflect_idx(y + 1 + r, Hh) * Ww];
            vo[q] = habb[(size_t)reflect_idx(y - r, Hh) * Ww];
            const size_t po = (size_t)y * Ww + j;
            cr[q] = imb[0*HWn + po];
            cg[q] = imb[1*HWn + po];
            cb[q] = imb[2*HWn + po];
        }
        #pragma unroll
        for (int q = 0; q < 4; ++q) {
            const int y = yb + q;
            const size_t po = (size_t)y * Ww + j;
            float g_ = 0.299f*cr[q] + 0.587f*cg[q] + 0.114f*cb[q];
            float t = fminf(fmaxf((V.x * g_ + V.y) * ikk, 0.1f), 1.0f);
            float invt = 1.0f / (t + 1e-8f);
            Jb[0*HWn + po] = fminf(fmaxf((cr[q] - Aa[0]) * invt + Aa[0], 0.f), 1.f);
            Jb[1*HWn + po] = fminf(fmaxf((cg[q] - Aa[1]) * invt + Aa[1], 0.f), 1.f);
            Jb[2*HWn + po] = fminf(fmaxf((cb[q] - Aa[2]) * invt + Aa[2], 0.f), 1.f);
            V.x += vi[q].x - vo[q].x;
            V.y += vi[q].y - vo[q].y;
        }
    }
}

// ---- K5a: per-(b,c) 1024-bin histogram of J, distributed over 768 blocks --
__global__ __launch_bounds__(256) void k5_hist(
    const float4* __restrict__ J, unsigned int* __restrict__ hist)
{
    const int bc  = blockIdx.x >> 5;          // 0..23
    const int sub = blockIdx.x & (NSUB - 1);
    const int tid = threadIdx.x;
    __shared__ unsigned int lh[NBIN];
    for (int i = tid; i < NBIN; i += 256) lh[i] = 0u;
    __syncthreads();

    const float4* base = J + (size_t)bc * (HWn / 4) + (size_t)sub * (HWn / 4 / NSUB);
    unsigned int clo = 0, chi = 0;
    for (int i = tid; i < HWn / 4 / NSUB; i += 256) {
        float4 v = base[i];
        #pragma unroll
        for (int c = 0; c < 4; ++c) {
            float f = (c == 0) ? v.x : (c == 1) ? v.y : (c == 2) ? v.z : v.w;
            int bin = (int)(f * (float)NBIN);
            bin = (bin > NBIN-1) ? NBIN-1 : bin;
            if (bin == 0)           clo++;
            else if (bin == NBIN-1) chi++;
            else atomicAdd(&lh[bin], 1u);
        }
    }
    if (clo) atomicAdd(&lh[0], clo);
    if (chi) atomicAdd(&lh[NBIN-1], chi);
    __syncthreads();
    for (int i = tid; i < NBIN; i += 256) {
        unsigned int v = lh[i];
        if (v) atomicAdd(&hist[(size_t)bc * NBIN + i], v);
    }
}

// ---- K5b: one wave per (target,bc): rank -> bin -> percentile value ------
__global__ __launch_bounds__(64) void k5_decide(
    const unsigned int* __restrict__ hist,      // [24][NBIN]
    const float* __restrict__ L_low, const float* __restrict__ L_high,
    float* __restrict__ p_low, float* __restrict__ p_high)
{
    const int t  = blockIdx.x / 24;
    const int bc = blockIdx.x % 24;
    const int b  = bc / 3;
    const int lane = threadIdx.x;
    const unsigned int* hb = hist + (size_t)bc * NBIN;

    unsigned int loc[NBIN / 64];
    unsigned int lsum = 0;
    #pragma unroll
    for (int i = 0; i < NBIN / 64; ++i) { loc[i] = hb[lane * (NBIN/64) + i]; lsum += loc[i]; }

    unsigned int incl = lsum;
    #pragma unroll
    for (int off = 1; off < 64; off <<= 1) {
        unsigned int v = __shfl_up(incl, off);
        if (lane >= off) incl += v;
    }
    unsigned int excl = incl - lsum;

    float L = t ? L_high[b] : L_low[b];
    int k = (int)(L * (1.0f / 100.0f) * (float)HWn);
    k = (k < 0) ? 0 : ((k > HWn - 1) ? HWn - 1 : k);

    if ((unsigned int)k >= excl && (unsigned int)k < incl) {
        unsigned int c = excl;
        #pragma unroll
        for (int i = 0; i < NBIN / 64; ++i) {
            if ((unsigned int)k < c + loc[i]) {
                float val = ((float)(lane * (NBIN/64) + i) + 0.5f) * (1.0f / (float)NBIN);
                if (t) p_high[bc] = val;
                else   p_low[bc]  = val;
                break;
            }
            c += loc[i];
        }
    }
}

// ---------------- K6: in-place percentile stretch (float4) ----------------
__global__ __launch_bounds__(256) void k6_norm(
    float4* __restrict__ J,
    const float* __restrict__ p_low, const float* __restrict__ p_high)
{
    size_t idx = (size_t)blockIdx.x * 256 + threadIdx.x;
    int bc = (int)(idx >> 16);           // HWn/4 == 2^16 float4s per (b,c)
    float l = p_low[bc], h = p_high[bc];
    float inv = 1.0f / (h - l + 1e-8f);
    float4 v = J[idx];
    v.x = fminf(fmaxf((fminf(fmaxf(v.x, l), h) - l) * inv, 0.f), 1.f);
    v.y = fminf(fmaxf((fminf(fmaxf(v.y, l), h) - l) * inv, 0.f), 1.f);
    v.z = fminf(fmaxf((fminf(fmaxf(v.z, l), h) - l) * inv, 0.f), 1.f);
    v.w = fminf(fmaxf((fminf(fmaxf(v.w, l), h) - l) * inv, 0.f), 1.f);
    J[idx] = v;
}

extern "C" void kernel_launch(void* const* d_in, const int* in_sizes, int n_in,
                              void* d_out, int out_size, void* d_ws, size_t ws_size,
                              hipStream_t stream)
{
    const float* img    = (const float*)d_in[0];
    const float* omega  = (const float*)d_in[1];
    const float* atm    = (const float*)d_in[2];
    const float* L_low  = (const float*)d_in[3];
    const float* L_high = (const float*)d_in[4];
    const int*   rad    = (const int*)d_in[5];
    float* J  = (float*)d_out;
    float* ws = (float*)d_ws;

    const size_t F = (size_t)Bb * HWn;           // 2097152 px per field
    float2* hab = (float2*)ws;                   // [0,2F) floats (16 MB)
    unsigned int* hist = (unsigned int*)(ws + 2 * F);   // [24][1024]
    float* pl = (float*)(hist + 24 * NBIN);
    float* ph = pl + 32;
    // k123 zeroes hist (48*512 = 24576 = 24*1024 uints) as a side duty.

    k123_fused<<<dim3(Hh/CHF, Bb), 512, 0, stream>>>(img, omega, atm, rad, hab, hist);
    k4_final_v<<<dim3(Hh/CHK4, Bb, 2), 256, 0, stream>>>(hab, img, atm, rad, J);
    k5_hist   <<<24 * NSUB, 256, 0, stream>>>((const float4*)J, hist);
    k5_decide <<<48, 64, 0, stream>>>(hist, L_low, L_high, pl, ph);
    k6_norm   <<<(int)(3 * F / 4 / 256), 256, 0, stream>>>((float4*)J, pl, ph);
}

// Round 16
// 166.657 us; speedup vs baseline: 1.1919x; 1.1919x over previous
//
#include <hip/hip_runtime.h>
#include <cstdint>

constexpr int Bb = 8, Hh = 512, Ww = 512;
constexpr int HWn = Hh * Ww;          // 262144 = 2^18
constexpr int CH23 = 16;              // rows per block in k23 (2-barrier structure)
constexpr int CHK4 = 8;               // rows per block in k4 (float4 version)
constexpr int NBIN = 1024;            // percentile histogram bins over [0,1]
constexpr int NSUB = 32;              // sub-blocks per (b,c) in k5_hist

__device__ __forceinline__ int reflect_idx(int p, int n) {
    p = (p < 0) ? -p : p;
    return (p < n) ? p : (2 * n - 2 - p);
}
__device__ __forceinline__ int clamp_r(const int* rad) {
    int r = rad[0];
    return (r < 1) ? 1 : ((r > 50) ? 50 : r);
}

// ---------------- K1: rows -> horizontal box sums (float4) ----------------
__global__ __launch_bounds__(512) void k1_stats_h(
    const float* __restrict__ img, const float* __restrict__ omega,
    const float* __restrict__ atm, const int* __restrict__ rad,
    float4* __restrict__ hq, unsigned int* __restrict__ histzero)
{
    const int i = blockIdx.x;
    const int b = blockIdx.y;
    const int j = threadIdx.x;           // 512 threads = one per column
    const int fbid = b * gridDim.x + i;
    if (fbid < 48) histzero[fbid * 512 + j] = 0u;   // zero 24*1024 hist bins
    const int r = clamp_r(rad);

    __shared__ float t0c[512], t0p[512];
    __shared__ float4 Pb[512];
    __shared__ float4 wsum[8];

    const float om = omega[b];
    const float iA0 = 1.0f / (atm[b*3+0] + 1e-8f);
    const float iA1 = 1.0f / (atm[b*3+1] + 1e-8f);
    const float iA2 = 1.0f / (atm[b*3+2] + 1e-8f);
    const float* imb = img + (size_t)b * 3 * HWn;
    const int ip = (i > 0) ? (i - 1) : 0;

    float r0 = imb[0*HWn + i*Ww + j];
    float g0 = imb[1*HWn + i*Ww + j];
    float b0 = imb[2*HWn + i*Ww + j];
    t0c[j] = 1.0f - om * fminf(fminf(r0*iA0, g0*iA1), b0*iA2);
    float r1 = imb[0*HWn + ip*Ww + j];
    float g1 = imb[1*HWn + ip*Ww + j];
    float b1 = imb[2*HWn + ip*Ww + j];
    t0p[j] = 1.0f - om * fminf(fminf(r1*iA0, g1*iA1), b1*iA2);
    float gr = 0.299f*r0 + 0.587f*g0 + 0.114f*b0;
    __syncthreads();

    float tx = (j == 0) ? t0p[0] : t0p[j-1] * __expf(-fabsf(t0p[j] - t0p[j-1]));
    float tgv = (i == 0) ? tx : tx * __expf(-fabsf(t0c[j] - t0p[j]));

    const int lane = j & 63, wv = j >> 6;
    float4 incl;
    incl.x = gr; incl.y = tgv; incl.z = gr * tgv; incl.w = gr * gr;
    #pragma unroll
    for (int off = 1; off < 64; off <<= 1) {
        float ux = __shfl_up(incl.x, off);
        float uy = __shfl_up(incl.y, off);
        float uz = __shfl_up(incl.z, off);
        float uw = __shfl_up(incl.w, off);
        if (lane >= off) { incl.x += ux; incl.y += uy; incl.z += uz; incl.w += uw; }
    }
    if (lane == 63) wsum[wv] = incl;
    __syncthreads();
    float4 o4; o4.x = 0.f; o4.y = 0.f; o4.z = 0.f; o4.w = 0.f;
    #pragma unroll
    for (int w = 0; w < 7; ++w) {
        if (w < wv) {
            float4 t = wsum[w];
            o4.x += t.x; o4.y += t.y; o4.z += t.z; o4.w += t.w;
        }
    }
    float4 P; P.x = incl.x + o4.x; P.y = incl.y + o4.y; P.z = incl.z + o4.z; P.w = incl.w + o4.w;
    Pb[j] = P;
    __syncthreads();

    const int lo = j - r, hi = j + r;
    float4 s = Pb[(hi > 511) ? 511 : hi];
    if (lo > 0) {
        float4 t = Pb[lo-1];
        s.x -= t.x; s.y -= t.y; s.z -= t.z; s.w -= t.w;
    }
    if (lo < 0) {
        float4 t = Pb[r - j], u = Pb[0];
        s.x += t.x - u.x; s.y += t.y - u.y; s.z += t.z - u.z; s.w += t.w - u.w;
    }
    if (hi > 511) {
        float4 t = Pb[510], u = Pb[1021 - j - r];
        s.x += t.x - u.x; s.y += t.y - u.y; s.z += t.z - u.z; s.w += t.w - u.w;
    }
    hq[((size_t)b * Hh + i) * Ww + j] = s;
}

// ---- K23: vertical sliding box on hq -> a,b (registers, barrier-free) ----
//      2-barrier structure, CH=16.
__global__ __launch_bounds__(512) void k23_ab_h(
    const float4* __restrict__ hq, const int* __restrict__ rad,
    float2* __restrict__ hab)
{
    const int b  = blockIdx.y;
    const int y0 = blockIdx.x * CH23;
    const int j  = threadIdx.x;
    const int r  = clamp_r(rad);
    const float ikk = 1.0f / (float)((2*r+1) * (2*r+1));
    const int lane = j & 63, wv = j >> 6;

    __shared__ float2 Pb8[CH23][512];    // 64 KB
    __shared__ float2 wsum8[CH23][8];

    float4 s; s.x = 0.f; s.y = 0.f; s.z = 0.f; s.w = 0.f;
    for (int d = -r; d <= r; ++d) {
        int m = reflect_idx(y0 + d, Hh);
        float4 v = hq[((size_t)b * Hh + m) * Ww + j];
        s.x += v.x; s.y += v.y; s.z += v.z; s.w += v.w;
    }
    float av[CH23], bv[CH23];
    #pragma unroll
    for (int k = 0; k < CH23; ++k) {
        int y = y0 + k;
        float mI = s.x * ikk, mp = s.y * ikk, mIp = s.z * ikk, mII = s.w * ikk;
        float a = (mIp - mI * mp) / (mII - mI * mI + 0.5f);
        av[k] = a;
        bv[k] = mp - a * mI;
        int yin  = reflect_idx(y + 1 + r, Hh);
        int yout = reflect_idx(y - r, Hh);
        float4 vi = hq[((size_t)b * Hh + yin)  * Ww + j];
        float4 vo = hq[((size_t)b * Hh + yout) * Ww + j];
        s.x += vi.x - vo.x; s.y += vi.y - vo.y; s.z += vi.z - vo.z; s.w += vi.w - vo.w;
    }

    float ix[CH23], iy[CH23];
    #pragma unroll
    for (int k = 0; k < CH23; ++k) {
        float sx = av[k], sy = bv[k];
        #pragma unroll
        for (int off = 1; off < 64; off <<= 1) {
            float ux = __shfl_up(sx, off);
            float uy = __shfl_up(sy, off);
            if (lane >= off) { sx += ux; sy += uy; }
        }
        ix[k] = sx; iy[k] = sy;
        if (lane == 63) { wsum8[k][wv].x = sx; wsum8[k][wv].y = sy; }
    }
    __syncthreads();

    #pragma unroll
    for (int k = 0; k < CH23; ++k) {
        float ox = 0.f, oy = 0.f;
        #pragma unroll
        for (int w = 0; w < 7; ++w) {
            if (w < wv) { float2 t = wsum8[k][w]; ox += t.x; oy += t.y; }
        }
        Pb8[k][j].x = ix[k] + ox;
        Pb8[k][j].y = iy[k] + oy;
    }
    __syncthreads();

    const int lo = j - r, hi = j + r;
    const int him = (hi > 511) ? 511 : hi;
    #pragma unroll
    for (int k = 0; k < CH23; ++k) {
        float2 hs = Pb8[k][him];
        if (lo > 0)   { float2 t = Pb8[k][lo-1];  hs.x -= t.x; hs.y -= t.y; }
        if (lo < 0)   { float2 t = Pb8[k][r-j], u = Pb8[k][0];
                        hs.x += t.x - u.x; hs.y += t.y - u.y; }
        if (hi > 511) { float2 t = Pb8[k][510], u = Pb8[k][1021-j-r];
                        hs.x += t.x - u.x; hs.y += t.y - u.y; }
        hab[((size_t)b * Hh + (y0 + k)) * Ww + j] = hs;
    }
}

// ---- K4: float4 version — each thread owns 4 columns; all memory ops 16B --
__global__ __launch_bounds__(128) void k4_final_v(
    const float4* __restrict__ hab4, const float4* __restrict__ img,
    const float* __restrict__ atm, const int* __restrict__ rad,
    float4* __restrict__ J)
{
    const int b  = blockIdx.y;
    const int y0 = blockIdx.x * CHK4;
    const int jc = threadIdx.x;              // float4 column 0..127
    const int r  = clamp_r(rad);
    const float ikk = 1.0f / (float)((2*r+1) * (2*r+1));
    const int HP = Ww / 2;                   // hab row pitch in float4 (256)
    const int CP = HWn / 4;                  // channel pitch in float4 (65536)
    const int RP = Ww / 4;                   // img/J row pitch in float4 (128)

    float A0 = atm[b*3+0], A1 = atm[b*3+1], A2 = atm[b*3+2];
    const float4* imb  = img  + (size_t)b * 3 * CP;
    float4*       Jb   = J    + (size_t)b * 3 * CP;
    const float4* habb = hab4 + (size_t)b * Hh * HP + jc * 2;

    float2 V[4];
    #pragma unroll
    for (int q = 0; q < 4; ++q) { V[q].x = 0.f; V[q].y = 0.f; }
    for (int d = -r; d <= r; ++d) {
        int m = reflect_idx(y0 + d, Hh);
        float4 h0 = habb[(size_t)m * HP];
        float4 h1 = habb[(size_t)m * HP + 1];
        V[0].x += h0.x; V[0].y += h0.y;
        V[1].x += h0.z; V[1].y += h0.w;
        V[2].x += h1.x; V[2].y += h1.y;
        V[3].x += h1.z; V[3].y += h1.w;
    }

    for (int y = y0; y < y0 + CHK4; ++y) {
        const int yin  = reflect_idx(y + 1 + r, Hh);
        const int yout = reflect_idx(y - r, Hh);
        float4 i0 = habb[(size_t)yin  * HP];
        float4 i1 = habb[(size_t)yin  * HP + 1];
        float4 o0 = habb[(size_t)yout * HP];
        float4 o1 = habb[(size_t)yout * HP + 1];
        const size_t po = (size_t)y * RP + jc;
        float4 c0 = imb[0*CP + po];
        float4 c1 = imb[1*CP + po];
        float4 c2 = imb[2*CP + po];

        float cr[4] = {c0.x, c0.y, c0.z, c0.w};
        float cg[4] = {c1.x, c1.y, c1.z, c1.w};
        float cb[4] = {c2.x, c2.y, c2.z, c2.w};
        float o0v[4], o1v[4], o2v[4];
        #pragma unroll
        for (int q = 0; q < 4; ++q) {
            float g_ = 0.299f*cr[q] + 0.587f*cg[q] + 0.114f*cb[q];
            float t = fminf(fmaxf((V[q].x * g_ + V[q].y) * ikk, 0.1f), 1.0f);
            float invt = 1.0f / (t + 1e-8f);
            o0v[q] = fminf(fmaxf((cr[q] - A0) * invt + A0, 0.f), 1.f);
            o1v[q] = fminf(fmaxf((cg[q] - A1) * invt + A1, 0.f), 1.f);
            o2v[q] = fminf(fmaxf((cb[q] - A2) * invt + A2, 0.f), 1.f);
        }
        Jb[0*CP + po] = make_float4(o0v[0], o0v[1], o0v[2], o0v[3]);
        Jb[1*CP + po] = make_float4(o1v[0], o1v[1], o1v[2], o1v[3]);
        Jb[2*CP + po] = make_float4(o2v[0], o2v[1], o2v[2], o2v[3]);

        V[0].x += i0.x - o0.x; V[0].y += i0.y - o0.y;
        V[1].x += i0.z - o0.z; V[1].y += i0.w - o0.w;
        V[2].x += i1.x - o1.x; V[2].y += i1.y - o1.y;
        V[3].x += i1.z - o1.z; V[3].y += i1.w - o1.w;
    }
}

// ---- K5a: per-(b,c) 1024-bin histogram of J, distributed over 768 blocks --
__global__ __launch_bounds__(256) void k5_hist(
    const float4* __restrict__ J, unsigned int* __restrict__ hist)
{
    const int bc  = blockIdx.x >> 5;          // 0..23
    const int sub = blockIdx.x & (NSUB - 1);
    const int tid = threadIdx.x;
    __shared__ unsigned int lh[NBIN];
    for (int i = tid; i < NBIN; i += 256) lh[i] = 0u;
    __syncthreads();

    const float4* base = J + (size_t)bc * (HWn / 4) + (size_t)sub * (HWn / 4 / NSUB);
    unsigned int clo = 0, chi = 0;
    for (int i = tid; i < HWn / 4 / NSUB; i += 256) {
        float4 v = base[i];
        #pragma unroll
        for (int c = 0; c < 4; ++c) {
            float f = (c == 0) ? v.x : (c == 1) ? v.y : (c == 2) ? v.z : v.w;
            int bin = (int)(f * (float)NBIN);
            bin = (bin > NBIN-1) ? NBIN-1 : bin;
            if (bin == 0)           clo++;
            else if (bin == NBIN-1) chi++;
            else atomicAdd(&lh[bin], 1u);
        }
    }
    if (clo) atomicAdd(&lh[0], clo);
    if (chi) atomicAdd(&lh[NBIN-1], chi);
    __syncthreads();
    for (int i = tid; i < NBIN; i += 256) {
        unsigned int v = lh[i];
        if (v) atomicAdd(&hist[(size_t)bc * NBIN + i], v);
    }
}

// ---- K5b: one wave per (target,bc): rank -> bin -> percentile value ------
__global__ __launch_bounds__(64) void k5_decide(
    const unsigned int* __restrict__ hist,      // [24][NBIN]
    const float* __restrict__ L_low, const float* __restrict__ L_high,
    float* __restrict__ p_low, float* __restrict__ p_high)
{
    const int t  = blockIdx.x / 24;
    const int bc = blockIdx.x % 24;
    const int b  = bc / 3;
    const int lane = threadIdx.x;
    const unsigned int* hb = hist + (size_t)bc * NBIN;

    unsigned int loc[NBIN / 64];
    unsigned int lsum = 0;
    #pragma unroll
    for (int i = 0; i < NBIN / 64; ++i) { loc[i] = hb[lane * (NBIN/64) + i]; lsum += loc[i]; }

    unsigned int incl = lsum;
    #pragma unroll
    for (int off = 1; off < 64; off <<= 1) {
        unsigned int v = __shfl_up(incl, off);
        if (lane >= off) incl += v;
    }
    unsigned int excl = incl - lsum;

    float L = t ? L_high[b] : L_low[b];
    int k = (int)(L * (1.0f / 100.0f) * (float)HWn);
    k = (k < 0) ? 0 : ((k > HWn - 1) ? HWn - 1 : k);

    if ((unsigned int)k >= excl && (unsigned int)k < incl) {
        unsigned int c = excl;
        #pragma unroll
        for (int i = 0; i < NBIN / 64; ++i) {
            if ((unsigned int)k < c + loc[i]) {
                float val = ((float)(lane * (NBIN/64) + i) + 0.5f) * (1.0f / (float)NBIN);
                if (t) p_high[bc] = val;
                else   p_low[bc]  = val;
                break;
            }
            c += loc[i];
        }
    }
}

// ---------------- K6: in-place percentile stretch (float4) ----------------
__global__ __launch_bounds__(256) void k6_norm(
    float4* __restrict__ J,
    const float* __restrict__ p_low, const float* __restrict__ p_high)
{
    size_t idx = (size_t)blockIdx.x * 256 + threadIdx.x;
    int bc = (int)(idx >> 16);           // HWn/4 == 2^16 float4s per (b,c)
    float l = p_low[bc], h = p_high[bc];
    float inv = 1.0f / (h - l + 1e-8f);
    float4 v = J[idx];
    v.x = fminf(fmaxf((fminf(fmaxf(v.x, l), h) - l) * inv, 0.f), 1.f);
    v.y = fminf(fmaxf((fminf(fmaxf(v.y, l), h) - l) * inv, 0.f), 1.f);
    v.z = fminf(fmaxf((fminf(fmaxf(v.z, l), h) - l) * inv, 0.f), 1.f);
    v.w = fminf(fmaxf((fminf(fmaxf(v.w, l), h) - l) * inv, 0.f), 1.f);
    J[idx] = v;
}

extern "C" void kernel_launch(void* const* d_in, const int* in_sizes, int n_in,
                              void* d_out, int out_size, void* d_ws, size_t ws_size,
                              hipStream_t stream)
{
    const float* img    = (const float*)d_in[0];
    const float* omega  = (const float*)d_in[1];
    const float* atm    = (const float*)d_in[2];
    const float* L_low  = (const float*)d_in[3];
    const float* L_high = (const float*)d_in[4];
    const int*   rad    = (const int*)d_in[5];
    float* J  = (float*)d_out;
    float* ws = (float*)d_ws;

    const size_t F = (size_t)Bb * HWn;           // 2097152 px per field
    float4* hq  = (float4*)ws;                   // [0,4F) floats (32 MB)
    float2* hab = (float2*)(ws + 4 * F);         // [4F,6F)      (16 MB)
    unsigned int* hist = (unsigned int*)(ws + 6 * F);   // [24][1024]
    float* pl = (float*)(hist + 24 * NBIN);
    float* ph = pl + 32;
    // k1 zeroes hist (48*512 = 24576 = 24*1024 uints) as a side duty.

    k1_stats_h<<<dim3(Hh, Bb), 512, 0, stream>>>(img, omega, atm, rad, hq, hist);
    k23_ab_h  <<<dim3(Hh/CH23, Bb), 512, 0, stream>>>(hq, rad, hab);
    k4_final_v<<<dim3(Hh/CHK4, Bb), 128, 0, stream>>>((const float4*)hab, (const float4*)img, atm, rad, (float4*)J);
    k5_hist   <<<24 * NSUB, 256, 0, stream>>>((const float4*)J, hist);
    k5_decide <<<48, 64, 0, stream>>>(hist, L_low, L_high, pl, ph);
    k6_norm   <<<(int)(3 * F / 4 / 256), 256, 0, stream>>>((float4*)J, pl, ph);
}